// Round 15
// baseline (97.552 us; speedup 1.0000x reference)
//
#include <hip/hip_runtime.h>
#include <math.h>

#define BB 4
#define LL 2048
#define KK 30
#define HIDD 128
#define EDGEE 16
#define NLL 3
#define NHH 4
#define SCALE_ 0.17677669529663687f  /* 32^-0.5 */
#define NROW 8192                    /* B*L */
#define NEDG 245760                  /* B*L*K */

typedef __attribute__((ext_vector_type(8))) short bf16x8;
typedef __attribute__((ext_vector_type(4))) float f32x4;

__device__ __forceinline__ ushort f2b(float f) {
    union { float f; uint u; } x; x.f = f;
    uint r = x.u + 0x7fff + ((x.u >> 16) & 1);   // RNE
    return (ushort)(r >> 16);
}
// DPP lane swaps (all VALU pipe, no LDS ops)
__device__ __forceinline__ float dpp_qx1(float x) {   // quad_perm [1,0,3,2]
    return __int_as_float(__builtin_amdgcn_mov_dpp(__float_as_int(x), 0xB1, 0xF, 0xF, true));
}
__device__ __forceinline__ float dpp_qx2(float x) {   // quad_perm [2,3,0,1]
    return __int_as_float(__builtin_amdgcn_mov_dpp(__float_as_int(x), 0x4E, 0xF, 0xF, true));
}
__device__ __forceinline__ float dpp_hmir(float x) {  // row_half_mirror (i -> 7-i per 8)
    return __int_as_float(__builtin_amdgcn_mov_dpp(__float_as_int(x), 0x141, 0xF, 0xF, true));
}

// ---------------------------------------------------------------------------
// Prep: y=0 weights -> transposed bf16 WbT[m][n][k];
//       y=1 MASKED edge bias ebm[layer][row][k][h] + global ids gidx[row][k];
//       y=2 h_nodes -> bf16 hb.
// ---------------------------------------------------------------------------
__global__ __launch_bounds__(256) void prep_kernel(
    const float* __restrict__ Wq, const float* __restrict__ Wk,
    const float* __restrict__ Wv, const float* __restrict__ Wo,
    const float* __restrict__ h_edges, const float* __restrict__ We,
    const float* __restrict__ be, const float* __restrict__ h_nodes,
    const int* __restrict__ edge_idxs, const float* __restrict__ mask,
    ushort* __restrict__ WbT, float* __restrict__ eb, int* __restrict__ gidx,
    ushort* __restrict__ hb)
{
    const int id = blockIdx.x * 256 + threadIdx.x;
    if (blockIdx.y == 0) {
        if (id < 12 * 128 * 128) {
            int m = id >> 14;
            int rem = id & 16383;
            int k = rem >> 7, n = rem & 127;
            int layer = m >> 2, p = m & 3;
            const float* src;
            if (p == 0)      src = Wq + (size_t)layer * 16384;
            else if (p == 1) src = Wk + (size_t)layer * 16384;
            else if (p == 2) src = Wv + (size_t)layer * 16384;
            else             src = Wo + (size_t)layer * 16384;
            WbT[(size_t)m * 16384 + n * 128 + k] = f2b(src[k * 128 + n]);
        }
    } else if (blockIdx.y == 1) {
        __shared__ float We_s[NLL * EDGEE * NHH];
        __shared__ float be_s[NLL * NHH];
        if (threadIdx.x < NLL * EDGEE * NHH) We_s[threadIdx.x] = We[threadIdx.x];
        if (threadIdx.x < NLL * NHH) be_s[threadIdx.x] = be[threadIdx.x];
        __syncthreads();
        if (id < NEDG) {
            int rowi = id / KK;                       // one-time cost
            int gid = (rowi >> 11) * LL + edge_idxs[id];
            float am = mask[rowi] * mask[gid];
            gidx[id] = gid;
            const float4* e4 = (const float4*)h_edges + (size_t)id * 4;
            float4 ec[4] = {e4[0], e4[1], e4[2], e4[3]};
            float ev[16];
            #pragma unroll
            for (int q = 0; q < 4; ++q) {
                ev[q * 4 + 0] = ec[q].x; ev[q * 4 + 1] = ec[q].y;
                ev[q * 4 + 2] = ec[q].z; ev[q * 4 + 3] = ec[q].w;
            }
            #pragma unroll
            for (int i = 0; i < NLL; ++i) {
                float r[NHH] = {be_s[i * 4], be_s[i * 4 + 1], be_s[i * 4 + 2], be_s[i * 4 + 3]};
                #pragma unroll
                for (int e = 0; e < EDGEE; ++e) {
                    float v = ev[e];
                    #pragma unroll
                    for (int hq = 0; hq < NHH; ++hq)
                        r[hq] = fmaf(v, We_s[i * 64 + e * NHH + hq], r[hq]);
                }
                float4 o = (am == 0.f) ? make_float4(-1e9f, -1e9f, -1e9f, -1e9f)
                                       : make_float4(r[0], r[1], r[2], r[3]);
                ((float4*)eb)[(size_t)i * NEDG + id] = o;
            }
        }
    } else {
        float4 v = ((const float4*)h_nodes)[id];
        ushort4 o;
        o.x = f2b(v.x); o.y = f2b(v.y); o.z = f2b(v.z); o.w = f2b(v.w);
        ((ushort4*)hb)[id] = o;
    }
}

// ---------------------------------------------------------------------------
// QKV via bf16 MFMA: out = hb @ W + b. Grid (64, 3proj), 256 thr, 128-tile.
// fp32 outputs.
// ---------------------------------------------------------------------------
__global__ __launch_bounds__(256) void qkv_mfma(
    const ushort* __restrict__ hb, const ushort* __restrict__ WbT,
    const float* __restrict__ bq, const float* __restrict__ bk,
    const float* __restrict__ bv,
    float* __restrict__ Qp, float* __restrict__ Kp, float* __restrict__ Vp)
{
    __shared__ ushort As[128 * 128];   // 32KB
    __shared__ ushort Bs[128 * 128];   // 32KB

    const int t = threadIdx.x;
    const int proj = blockIdx.y;
    const ushort* W = WbT + (size_t)proj * 16384;
    const float* bias = proj == 0 ? bq : (proj == 1 ? bk : bv);
    float* out = proj == 0 ? Qp : (proj == 1 ? Kp : Vp);
    const int row0 = blockIdx.x * 128;

    const uint4* hb4 = (const uint4*)(hb + (size_t)row0 * 128);
    const uint4* W4 = (const uint4*)W;
    #pragma unroll
    for (int i = 0; i < 8; ++i) {
        int c = t + i * 256;
        int r = c >> 4, kc = c & 15;
        int off = (r * 256 + kc * 16) ^ ((r & 7) << 4);
        *(uint4*)((char*)As + off) = hb4[c];
        *(uint4*)((char*)Bs + off) = W4[c];
    }
    __syncthreads();

    const int wid = t >> 6, l = t & 63;
    const int lr = l & 15, lg = l >> 4;
    const int rbase = wid * 32;
    f32x4 acc[2][8];
    #pragma unroll
    for (int m = 0; m < 2; ++m)
        #pragma unroll
        for (int n = 0; n < 8; ++n) acc[m][n] = (f32x4){0.f, 0.f, 0.f, 0.f};

    #pragma unroll
    for (int ks = 0; ks < 4; ++ks) {
        const int kb = (lg * 8 + ks * 32) * 2;
        bf16x8 a[2], b[8];
        #pragma unroll
        for (int m = 0; m < 2; ++m) {
            int row = rbase + m * 16 + lr;
            a[m] = *(const bf16x8*)((const char*)As + ((row * 256 + kb) ^ ((row & 7) << 4)));
        }
        #pragma unroll
        for (int n = 0; n < 8; ++n) {
            int col = n * 16 + lr;
            b[n] = *(const bf16x8*)((const char*)Bs + ((col * 256 + kb) ^ ((col & 7) << 4)));
        }
        #pragma unroll
        for (int m = 0; m < 2; ++m)
            #pragma unroll
            for (int n = 0; n < 8; ++n)
                acc[m][n] = __builtin_amdgcn_mfma_f32_16x16x32_bf16(a[m], b[n], acc[m][n], 0, 0, 0);
    }

    #pragma unroll
    for (int n = 0; n < 8; ++n) {
        int col = n * 16 + lr;
        float bc = bias[col];
        #pragma unroll
        for (int m = 0; m < 2; ++m)
            #pragma unroll
            for (int r = 0; r < 4; ++r) {
                int row = row0 + rbase + m * 16 + lg * 4 + r;
                out[(size_t)row * 128 + col] = acc[m][n][r] + bc;
            }
    }
}

// ---------------------------------------------------------------------------
// Attention v10 = R14 with mask pre-folded into eb (no ams array, no
// cndmask) and widx hoisted to registers (30 LDS reads instead of 60).
// ---------------------------------------------------------------------------
__global__ __launch_bounds__(256) void attn_kernel(
    const float* __restrict__ Qp, const float* __restrict__ Kp,
    const float* __restrict__ Vp,
    const int* __restrict__ gidx, const float4* __restrict__ ebL,
    ushort* __restrict__ o_out)
{
    __shared__ int   widx[8][KK];
    __shared__ float ebs[8][KK][NHH];

    // XCD swizzle: hw blocks on XCD x (bid%8==x) process logical blocks
    // [x*128, x*128+128) -> rows [x*1024, x*1024+1024) (single batch slice).
    const int lbid = (blockIdx.x & 7) * 128 + (blockIdx.x >> 3);

    const int t = threadIdx.x;
    const int grp = t >> 5;
    const int g = t & 31;
    const int row = lbid * 8 + grp;
    const int hh = g >> 3;

    if (g < KK) {
        widx[grp][g] = gidx[(size_t)row * KK + g];
        *(float4*)&ebs[grp][g][0] = ebL[(size_t)row * KK + g];
    }
    __syncthreads();

    int wreg[KK];
    #pragma unroll
    for (int k = 0; k < KK; ++k) wreg[k] = widx[grp][k];

    const float4* Kp4 = (const float4*)Kp;
    const float4* Vp4 = (const float4*)Vp;
    const float4 q4 = ((const float4*)Qp)[(size_t)row * 32 + g];

    float sc[KK];
    // K phase: 3 batches of 10 in-flight gathers
    #pragma unroll
    for (int kb = 0; kb < 3; ++kb) {
        float4 kv[10];
        #pragma unroll
        for (int j = 0; j < 10; ++j)
            kv[j] = Kp4[(size_t)wreg[kb * 10 + j] * 32 + g];
        #pragma unroll
        for (int j = 0; j < 10; ++j) {
            int k = kb * 10 + j;
            float p = q4.x * kv[j].x + q4.y * kv[j].y + q4.z * kv[j].z + q4.w * kv[j].w;
            p += dpp_qx1(p);     // lane^1 (quad_perm, VALU)
            p += dpp_qx2(p);     // lane^2 (quad_perm, VALU)
            p += dpp_hmir(p);    // other quad of the 8-lane head group (VALU)
            sc[k] = fmaf(p, SCALE_, ebs[grp][k][hh]);
        }
    }

    float m = sc[0];
    #pragma unroll
    for (int k = 1; k < KK; ++k) m = fmaxf(m, sc[k]);
    float sum = 0.f;
    #pragma unroll
    for (int k = 0; k < KK; ++k) { sc[k] = __expf(sc[k] - m); sum += sc[k]; }
    const float inv = 1.f / sum;

    float4 o = make_float4(0.f, 0.f, 0.f, 0.f);
    // V phase: 3 batches of 10 in-flight gathers
    #pragma unroll
    for (int kb = 0; kb < 3; ++kb) {
        float4 vv[10];
        #pragma unroll
        for (int j = 0; j < 10; ++j)
            vv[j] = Vp4[(size_t)wreg[kb * 10 + j] * 32 + g];
        #pragma unroll
        for (int j = 0; j < 10; ++j) {
            float w = sc[kb * 10 + j];
            o.x = fmaf(w, vv[j].x, o.x);
            o.y = fmaf(w, vv[j].y, o.y);
            o.z = fmaf(w, vv[j].z, o.z);
            o.w = fmaf(w, vv[j].w, o.w);
        }
    }
    ushort ob[4] = {f2b(o.x * inv), f2b(o.y * inv), f2b(o.z * inv), f2b(o.w * inv)};
    *(uint2*)&o_out[(size_t)row * HIDD + g * 4] = *(uint2*)ob;
}

// ---------------------------------------------------------------------------
// Outproj via bf16 MFMA + bias + residual + LN + mask. 128-tile, grid 64.
// Writes fp32 h (or d_out) AND bf16 hb for next layer's qkv.
// ---------------------------------------------------------------------------
__global__ __launch_bounds__(256) void outproj_mfma(
    const ushort* __restrict__ obb, const ushort* __restrict__ WoT,
    const float* __restrict__ bo, const float* __restrict__ hres,
    const float* __restrict__ g, const float* __restrict__ bb,
    const float* __restrict__ mask, float* __restrict__ hout,
    ushort* __restrict__ hbout)
{
    __shared__ ushort As[128 * 128];
    __shared__ ushort Bs[128 * 128];

    const int t = threadIdx.x;
    const int row0 = blockIdx.x * 128;

    const uint4* A4 = (const uint4*)(obb + (size_t)row0 * 128);
    const uint4* W4 = (const uint4*)WoT;
    #pragma unroll
    for (int i = 0; i < 8; ++i) {
        int c = t + i * 256;
        int r = c >> 4, kc = c & 15;
        int off = (r * 256 + kc * 16) ^ ((r & 7) << 4);
        *(uint4*)((char*)As + off) = A4[c];
        *(uint4*)((char*)Bs + off) = W4[c];
    }
    __syncthreads();

    const int wid = t >> 6, l = t & 63;
    const int lr = l & 15, lg = l >> 4;
    const int rbase = wid * 32;
    f32x4 acc[2][8];
    #pragma unroll
    for (int m = 0; m < 2; ++m)
        #pragma unroll
        for (int n = 0; n < 8; ++n) acc[m][n] = (f32x4){0.f, 0.f, 0.f, 0.f};

    #pragma unroll
    for (int ks = 0; ks < 4; ++ks) {
        const int kb = (lg * 8 + ks * 32) * 2;
        bf16x8 a[2], b[8];
        #pragma unroll
        for (int m = 0; m < 2; ++m) {
            int row = rbase + m * 16 + lr;
            a[m] = *(const bf16x8*)((const char*)As + ((row * 256 + kb) ^ ((row & 7) << 4)));
        }
        #pragma unroll
        for (int n = 0; n < 8; ++n) {
            int col = n * 16 + lr;
            b[n] = *(const bf16x8*)((const char*)Bs + ((col * 256 + kb) ^ ((col & 7) << 4)));
        }
        #pragma unroll
        for (int m = 0; m < 2; ++m)
            #pragma unroll
            for (int n = 0; n < 8; ++n)
                acc[m][n] = __builtin_amdgcn_mfma_f32_16x16x32_bf16(a[m], b[n], acc[m][n], 0, 0, 0);
    }

    float s1[2][4] = {}, s2[2][4] = {};
    #pragma unroll
    for (int n = 0; n < 8; ++n) {
        int col = n * 16 + lr;
        float boc = bo[col];
        #pragma unroll
        for (int m = 0; m < 2; ++m)
            #pragma unroll
            for (int r = 0; r < 4; ++r) {
                int row = row0 + rbase + m * 16 + lg * 4 + r;
                float v = acc[m][n][r] + boc + hres[(size_t)row * 128 + col];
                acc[m][n][r] = v;
                s1[m][r] += v;
                s2[m][r] += v * v;
            }
    }
    #pragma unroll
    for (int m = 0; m < 2; ++m)
        #pragma unroll
        for (int r = 0; r < 4; ++r) {
            float a = s1[m][r], b2 = s2[m][r];
            #pragma unroll
            for (int d = 1; d < 16; d <<= 1) {
                a  += __shfl_xor(a, d, 64);
                b2 += __shfl_xor(b2, d, 64);
            }
            s1[m][r] = a; s2[m][r] = b2;
        }

    float gv[8], bbv[8];
    #pragma unroll
    for (int n = 0; n < 8; ++n) { gv[n] = g[n * 16 + lr]; bbv[n] = bb[n * 16 + lr]; }

    #pragma unroll
    for (int m = 0; m < 2; ++m)
        #pragma unroll
        for (int r = 0; r < 4; ++r) {
            int row = row0 + rbase + m * 16 + lg * 4 + r;
            float mu = s1[m][r] * (1.f / 128.f);
            float var = s2[m][r] * (1.f / 128.f) - mu * mu;
            float rs = rsqrtf(var + 1e-5f);
            float mk = mask[row];
            #pragma unroll
            for (int n = 0; n < 8; ++n) {
                int col = n * 16 + lr;
                float val = ((acc[m][n][r] - mu) * rs * gv[n] + bbv[n]) * mk;
                hout[(size_t)row * 128 + col] = val;
                hbout[(size_t)row * 128 + col] = f2b(val);
            }
        }
}

extern "C" void kernel_launch(void* const* d_in, const int* in_sizes, int n_in,
                              void* d_out, int out_size, void* d_ws, size_t ws_size,
                              hipStream_t stream) {
    const float* h_nodes = (const float*)d_in[0];
    const float* h_edges = (const float*)d_in[1];
    const float* mask    = (const float*)d_in[2];
    const float* Wq = (const float*)d_in[3];
    const float* bq = (const float*)d_in[4];
    const float* Wk = (const float*)d_in[5];
    const float* bk = (const float*)d_in[6];
    const float* Wv = (const float*)d_in[7];
    const float* bv = (const float*)d_in[8];
    const float* We = (const float*)d_in[9];
    const float* be = (const float*)d_in[10];
    const float* Wo = (const float*)d_in[11];
    const float* bo = (const float*)d_in[12];
    const float* ln_g = (const float*)d_in[13];
    const float* ln_b = (const float*)d_in[14];
    const int* edge_idxs = (const int*)d_in[15];

    float* ws = (float*)d_ws;
    const size_t NE = (size_t)NROW * HIDD;         // 1048576
    float* h   = ws;
    float* Qp  = ws + NE;
    float* Kp  = ws + 2 * NE;
    float* Vp  = ws + 3 * NE;
    ushort* obb = (ushort*)(ws + 4 * NE);          // NE bf16
    ushort* hb  = obb + NE;                        // NE bf16
    ushort* WbT = hb + NE;                         // 12*16384 bf16
    float* eb   = (float*)(WbT + 12 * 16384);      // 3*NEDG*4 fp32
    int* gidx   = (int*)(eb + (size_t)3 * NEDG * 4); // NEDG ints

    prep_kernel<<<dim3(1024, 3), 256, 0, stream>>>(
        Wq, Wk, Wv, Wo, h_edges, We, be, h_nodes, edge_idxs, mask,
        WbT, eb, gidx, hb);

    for (int i = 0; i < NLL; ++i) {
        qkv_mfma<<<dim3(NROW / 128, 3), 256, 0, stream>>>(
            hb, WbT + (size_t)i * 4 * 16384,
            bq + i * HIDD, bk + i * HIDD, bv + i * HIDD,
            Qp, Kp, Vp);
        attn_kernel<<<NROW / 8, 256, 0, stream>>>(
            Qp, Kp, Vp, gidx,
            (const float4*)eb + (size_t)i * NEDG, obb);
        bool last = (i == NLL - 1);
        outproj_mfma<<<NROW / 128, 256, 0, stream>>>(
            obb, WbT + ((size_t)i * 4 + 3) * 16384, bo + i * HIDD,
            (i == 0) ? h_nodes : h,
            ln_g + i * HIDD, ln_b + i * HIDD, mask,
            last ? (float*)d_out : h, hb);
    }
}

// Round 16
// 94.694 us; speedup vs baseline: 1.0302x; 1.0302x over previous
//
#include <hip/hip_runtime.h>
#include <math.h>

#define BB 4
#define LL 2048
#define KK 30
#define HIDD 128
#define EDGEE 16
#define NLL 3
#define NHH 4
#define SCALE_ 0.17677669529663687f  /* 32^-0.5 */
#define NROW 8192                    /* B*L */
#define NEDG 245760                  /* B*L*K */

typedef __attribute__((ext_vector_type(8))) short bf16x8;
typedef __attribute__((ext_vector_type(4))) float f32x4;

__device__ __forceinline__ ushort f2b(float f) {
    union { float f; uint u; } x; x.f = f;
    uint r = x.u + 0x7fff + ((x.u >> 16) & 1);   // RNE
    return (ushort)(r >> 16);
}
// DPP lane swaps (all VALU pipe, no LDS ops)
__device__ __forceinline__ float dpp_qx1(float x) {   // quad_perm [1,0,3,2]
    return __int_as_float(__builtin_amdgcn_mov_dpp(__float_as_int(x), 0xB1, 0xF, 0xF, true));
}
__device__ __forceinline__ float dpp_qx2(float x) {   // quad_perm [2,3,0,1]
    return __int_as_float(__builtin_amdgcn_mov_dpp(__float_as_int(x), 0x4E, 0xF, 0xF, true));
}
__device__ __forceinline__ float dpp_hmir(float x) {  // row_half_mirror (i -> 7-i per 8)
    return __int_as_float(__builtin_amdgcn_mov_dpp(__float_as_int(x), 0x141, 0xF, 0xF, true));
}

// ---------------------------------------------------------------------------
// Prep: y=0 weights -> transposed bf16 WbT[m][n][k];
//       y=1 edge bias eb[layer][row][k][h] for all 3 layers;
//       y=2 h_nodes -> bf16 hb.
// ---------------------------------------------------------------------------
__global__ __launch_bounds__(256) void prep_kernel(
    const float* __restrict__ Wq, const float* __restrict__ Wk,
    const float* __restrict__ Wv, const float* __restrict__ Wo,
    const float* __restrict__ h_edges, const float* __restrict__ We,
    const float* __restrict__ be, const float* __restrict__ h_nodes,
    ushort* __restrict__ WbT, float* __restrict__ eb, ushort* __restrict__ hb)
{
    const int id = blockIdx.x * 256 + threadIdx.x;
    if (blockIdx.y == 0) {
        if (id < 12 * 128 * 128) {
            int m = id >> 14;
            int rem = id & 16383;
            int k = rem >> 7, n = rem & 127;
            int layer = m >> 2, p = m & 3;
            const float* src;
            if (p == 0)      src = Wq + (size_t)layer * 16384;
            else if (p == 1) src = Wk + (size_t)layer * 16384;
            else if (p == 2) src = Wv + (size_t)layer * 16384;
            else             src = Wo + (size_t)layer * 16384;
            WbT[(size_t)m * 16384 + n * 128 + k] = f2b(src[k * 128 + n]);
        }
    } else if (blockIdx.y == 1) {
        __shared__ float We_s[NLL * EDGEE * NHH];
        __shared__ float be_s[NLL * NHH];
        if (threadIdx.x < NLL * EDGEE * NHH) We_s[threadIdx.x] = We[threadIdx.x];
        if (threadIdx.x < NLL * NHH) be_s[threadIdx.x] = be[threadIdx.x];
        __syncthreads();
        if (id < NEDG) {
            const float4* e4 = (const float4*)h_edges + (size_t)id * 4;
            float4 ec[4] = {e4[0], e4[1], e4[2], e4[3]};
            float ev[16];
            #pragma unroll
            for (int q = 0; q < 4; ++q) {
                ev[q * 4 + 0] = ec[q].x; ev[q * 4 + 1] = ec[q].y;
                ev[q * 4 + 2] = ec[q].z; ev[q * 4 + 3] = ec[q].w;
            }
            #pragma unroll
            for (int i = 0; i < NLL; ++i) {
                float r[NHH] = {be_s[i * 4], be_s[i * 4 + 1], be_s[i * 4 + 2], be_s[i * 4 + 3]};
                #pragma unroll
                for (int e = 0; e < EDGEE; ++e) {
                    float v = ev[e];
                    #pragma unroll
                    for (int hq = 0; hq < NHH; ++hq)
                        r[hq] = fmaf(v, We_s[i * 64 + e * NHH + hq], r[hq]);
                }
                ((float4*)eb)[(size_t)i * NEDG + id] = make_float4(r[0], r[1], r[2], r[3]);
            }
        }
    } else {
        float4 v = ((const float4*)h_nodes)[id];
        ushort4 o;
        o.x = f2b(v.x); o.y = f2b(v.y); o.z = f2b(v.z); o.w = f2b(v.w);
        ((ushort4*)hb)[id] = o;
    }
}

// ---------------------------------------------------------------------------
// QKV via bf16 MFMA: out = hb @ W + b. Grid (64, 3proj), 256 thr, 128-tile.
// fp32 outputs.
// ---------------------------------------------------------------------------
__global__ __launch_bounds__(256) void qkv_mfma(
    const ushort* __restrict__ hb, const ushort* __restrict__ WbT,
    const float* __restrict__ bq, const float* __restrict__ bk,
    const float* __restrict__ bv,
    float* __restrict__ Qp, float* __restrict__ Kp, float* __restrict__ Vp)
{
    __shared__ ushort As[128 * 128];   // 32KB
    __shared__ ushort Bs[128 * 128];   // 32KB

    const int t = threadIdx.x;
    const int proj = blockIdx.y;
    const ushort* W = WbT + (size_t)proj * 16384;
    const float* bias = proj == 0 ? bq : (proj == 1 ? bk : bv);
    float* out = proj == 0 ? Qp : (proj == 1 ? Kp : Vp);
    const int row0 = blockIdx.x * 128;

    const uint4* hb4 = (const uint4*)(hb + (size_t)row0 * 128);
    const uint4* W4 = (const uint4*)W;
    #pragma unroll
    for (int i = 0; i < 8; ++i) {
        int c = t + i * 256;
        int r = c >> 4, kc = c & 15;
        int off = (r * 256 + kc * 16) ^ ((r & 7) << 4);
        *(uint4*)((char*)As + off) = hb4[c];
        *(uint4*)((char*)Bs + off) = W4[c];
    }
    __syncthreads();

    const int wid = t >> 6, l = t & 63;
    const int lr = l & 15, lg = l >> 4;
    const int rbase = wid * 32;
    f32x4 acc[2][8];
    #pragma unroll
    for (int m = 0; m < 2; ++m)
        #pragma unroll
        for (int n = 0; n < 8; ++n) acc[m][n] = (f32x4){0.f, 0.f, 0.f, 0.f};

    #pragma unroll
    for (int ks = 0; ks < 4; ++ks) {
        const int kb = (lg * 8 + ks * 32) * 2;
        bf16x8 a[2], b[8];
        #pragma unroll
        for (int m = 0; m < 2; ++m) {
            int row = rbase + m * 16 + lr;
            a[m] = *(const bf16x8*)((const char*)As + ((row * 256 + kb) ^ ((row & 7) << 4)));
        }
        #pragma unroll
        for (int n = 0; n < 8; ++n) {
            int col = n * 16 + lr;
            b[n] = *(const bf16x8*)((const char*)Bs + ((col * 256 + kb) ^ ((col & 7) << 4)));
        }
        #pragma unroll
        for (int m = 0; m < 2; ++m)
            #pragma unroll
            for (int n = 0; n < 8; ++n)
                acc[m][n] = __builtin_amdgcn_mfma_f32_16x16x32_bf16(a[m], b[n], acc[m][n], 0, 0, 0);
    }

    #pragma unroll
    for (int n = 0; n < 8; ++n) {
        int col = n * 16 + lr;
        float bc = bias[col];
        #pragma unroll
        for (int m = 0; m < 2; ++m)
            #pragma unroll
            for (int r = 0; r < 4; ++r) {
                int row = row0 + rbase + m * 16 + lg * 4 + r;
                out[(size_t)row * 128 + col] = acc[m][n][r] + bc;
            }
    }
}

// ---------------------------------------------------------------------------
// Attention (best: R14): 32 lanes/row, 10-deep gather batching, XCD swizzle,
// 8-lane dot reduction entirely on the VALU pipe via DPP.
// ---------------------------------------------------------------------------
__global__ __launch_bounds__(256) void attn_kernel(
    const float* __restrict__ Qp, const float* __restrict__ Kp,
    const float* __restrict__ Vp,
    const int* __restrict__ edge_idxs, const float4* __restrict__ ebL,
    const float* __restrict__ mask, ushort* __restrict__ o_out)
{
    __shared__ int   widx[8][KK];
    __shared__ float ams[8][KK];
    __shared__ float ebs[8][KK][NHH];

    // XCD swizzle: hw blocks on XCD x (bid%8==x) process logical blocks
    // [x*128, x*128+128) -> rows [x*1024, x*1024+1024) (single batch slice).
    const int lbid = (blockIdx.x & 7) * 128 + (blockIdx.x >> 3);

    const int t = threadIdx.x;
    const int grp = t >> 5;
    const int g = t & 31;
    const int row = lbid * 8 + grp;
    const int b = row >> 11;
    const int hh = g >> 3;

    if (g < KK) {
        int gid = b * LL + edge_idxs[(size_t)row * KK + g];
        widx[grp][g] = gid;
        ams[grp][g] = mask[row] * mask[gid];
        *(float4*)&ebs[grp][g][0] = ebL[(size_t)row * KK + g];
    }
    __syncthreads();

    const float4* Kp4 = (const float4*)Kp;
    const float4* Vp4 = (const float4*)Vp;
    const float4 q4 = ((const float4*)Qp)[(size_t)row * 32 + g];

    float sc[KK];
    // K phase: 3 batches of 10 in-flight gathers
    #pragma unroll
    for (int kb = 0; kb < 3; ++kb) {
        float4 kv[10];
        #pragma unroll
        for (int j = 0; j < 10; ++j)
            kv[j] = Kp4[(size_t)widx[grp][kb * 10 + j] * 32 + g];
        #pragma unroll
        for (int j = 0; j < 10; ++j) {
            int k = kb * 10 + j;
            float p = q4.x * kv[j].x + q4.y * kv[j].y + q4.z * kv[j].z + q4.w * kv[j].w;
            p += dpp_qx1(p);     // lane^1 (quad_perm, VALU)
            p += dpp_qx2(p);     // lane^2 (quad_perm, VALU)
            p += dpp_hmir(p);    // other quad of the 8-lane head group (VALU)
            float am = ams[grp][k];
            float ebv = ebs[grp][k][hh];
            sc[k] = (am == 0.f) ? -1e9f : fmaf(p, SCALE_, ebv);
        }
    }

    float m = sc[0];
    #pragma unroll
    for (int k = 1; k < KK; ++k) m = fmaxf(m, sc[k]);
    float sum = 0.f;
    #pragma unroll
    for (int k = 0; k < KK; ++k) { sc[k] = __expf(sc[k] - m); sum += sc[k]; }
    const float inv = 1.f / sum;

    float4 o = make_float4(0.f, 0.f, 0.f, 0.f);
    // V phase: 3 batches of 10 in-flight gathers
    #pragma unroll
    for (int kb = 0; kb < 3; ++kb) {
        float4 vv[10];
        #pragma unroll
        for (int j = 0; j < 10; ++j)
            vv[j] = Vp4[(size_t)widx[grp][kb * 10 + j] * 32 + g];
        #pragma unroll
        for (int j = 0; j < 10; ++j) {
            float w = sc[kb * 10 + j];
            o.x = fmaf(w, vv[j].x, o.x);
            o.y = fmaf(w, vv[j].y, o.y);
            o.z = fmaf(w, vv[j].z, o.z);
            o.w = fmaf(w, vv[j].w, o.w);
        }
    }
    ushort ob[4] = {f2b(o.x * inv), f2b(o.y * inv), f2b(o.z * inv), f2b(o.w * inv)};
    *(uint2*)&o_out[(size_t)row * HIDD + g * 4] = *(uint2*)ob;
}

// ---------------------------------------------------------------------------
// Outproj via bf16 MFMA + bias + residual + LN + mask. 128-tile, grid 64.
// Writes fp32 h (or d_out) AND bf16 hb for next layer's qkv.
// ---------------------------------------------------------------------------
__global__ __launch_bounds__(256) void outproj_mfma(
    const ushort* __restrict__ obb, const ushort* __restrict__ WoT,
    const float* __restrict__ bo, const float* __restrict__ hres,
    const float* __restrict__ g, const float* __restrict__ bb,
    const float* __restrict__ mask, float* __restrict__ hout,
    ushort* __restrict__ hbout)
{
    __shared__ ushort As[128 * 128];
    __shared__ ushort Bs[128 * 128];

    const int t = threadIdx.x;
    const int row0 = blockIdx.x * 128;

    const uint4* A4 = (const uint4*)(obb + (size_t)row0 * 128);
    const uint4* W4 = (const uint4*)WoT;
    #pragma unroll
    for (int i = 0; i < 8; ++i) {
        int c = t + i * 256;
        int r = c >> 4, kc = c & 15;
        int off = (r * 256 + kc * 16) ^ ((r & 7) << 4);
        *(uint4*)((char*)As + off) = A4[c];
        *(uint4*)((char*)Bs + off) = W4[c];
    }
    __syncthreads();

    const int wid = t >> 6, l = t & 63;
    const int lr = l & 15, lg = l >> 4;
    const int rbase = wid * 32;
    f32x4 acc[2][8];
    #pragma unroll
    for (int m = 0; m < 2; ++m)
        #pragma unroll
        for (int n = 0; n < 8; ++n) acc[m][n] = (f32x4){0.f, 0.f, 0.f, 0.f};

    #pragma unroll
    for (int ks = 0; ks < 4; ++ks) {
        const int kb = (lg * 8 + ks * 32) * 2;
        bf16x8 a[2], b[8];
        #pragma unroll
        for (int m = 0; m < 2; ++m) {
            int row = rbase + m * 16 + lr;
            a[m] = *(const bf16x8*)((const char*)As + ((row * 256 + kb) ^ ((row & 7) << 4)));
        }
        #pragma unroll
        for (int n = 0; n < 8; ++n) {
            int col = n * 16 + lr;
            b[n] = *(const bf16x8*)((const char*)Bs + ((col * 256 + kb) ^ ((col & 7) << 4)));
        }
        #pragma unroll
        for (int m = 0; m < 2; ++m)
            #pragma unroll
            for (int n = 0; n < 8; ++n)
                acc[m][n] = __builtin_amdgcn_mfma_f32_16x16x32_bf16(a[m], b[n], acc[m][n], 0, 0, 0);
    }

    float s1[2][4] = {}, s2[2][4] = {};
    #pragma unroll
    for (int n = 0; n < 8; ++n) {
        int col = n * 16 + lr;
        float boc = bo[col];
        #pragma unroll
        for (int m = 0; m < 2; ++m)
            #pragma unroll
            for (int r = 0; r < 4; ++r) {
                int row = row0 + rbase + m * 16 + lg * 4 + r;
                float v = acc[m][n][r] + boc + hres[(size_t)row * 128 + col];
                acc[m][n][r] = v;
                s1[m][r] += v;
                s2[m][r] += v * v;
            }
    }
    #pragma unroll
    for (int m = 0; m < 2; ++m)
        #pragma unroll
        for (int r = 0; r < 4; ++r) {
            float a = s1[m][r], b2 = s2[m][r];
            #pragma unroll
            for (int d = 1; d < 16; d <<= 1) {
                a  += __shfl_xor(a, d, 64);
                b2 += __shfl_xor(b2, d, 64);
            }
            s1[m][r] = a; s2[m][r] = b2;
        }

    float gv[8], bbv[8];
    #pragma unroll
    for (int n = 0; n < 8; ++n) { gv[n] = g[n * 16 + lr]; bbv[n] = bb[n * 16 + lr]; }

    #pragma unroll
    for (int m = 0; m < 2; ++m)
        #pragma unroll
        for (int r = 0; r < 4; ++r) {
            int row = row0 + rbase + m * 16 + lg * 4 + r;
            float mu = s1[m][r] * (1.f / 128.f);
            float var = s2[m][r] * (1.f / 128.f) - mu * mu;
            float rs = rsqrtf(var + 1e-5f);
            float mk = mask[row];
            #pragma unroll
            for (int n = 0; n < 8; ++n) {
                int col = n * 16 + lr;
                float val = ((acc[m][n][r] - mu) * rs * gv[n] + bbv[n]) * mk;
                hout[(size_t)row * 128 + col] = val;
                hbout[(size_t)row * 128 + col] = f2b(val);
            }
        }
}

extern "C" void kernel_launch(void* const* d_in, const int* in_sizes, int n_in,
                              void* d_out, int out_size, void* d_ws, size_t ws_size,
                              hipStream_t stream) {
    const float* h_nodes = (const float*)d_in[0];
    const float* h_edges = (const float*)d_in[1];
    const float* mask    = (const float*)d_in[2];
    const float* Wq = (const float*)d_in[3];
    const float* bq = (const float*)d_in[4];
    const float* Wk = (const float*)d_in[5];
    const float* bk = (const float*)d_in[6];
    const float* Wv = (const float*)d_in[7];
    const float* bv = (const float*)d_in[8];
    const float* We = (const float*)d_in[9];
    const float* be = (const float*)d_in[10];
    const float* Wo = (const float*)d_in[11];
    const float* bo = (const float*)d_in[12];
    const float* ln_g = (const float*)d_in[13];
    const float* ln_b = (const float*)d_in[14];
    const int* edge_idxs = (const int*)d_in[15];

    float* ws = (float*)d_ws;
    const size_t NE = (size_t)NROW * HIDD;         // 1048576
    float* h   = ws;
    float* Qp  = ws + NE;
    float* Kp  = ws + 2 * NE;
    float* Vp  = ws + 3 * NE;
    ushort* obb = (ushort*)(ws + 4 * NE);          // NE bf16
    ushort* hb  = obb + NE;                        // NE bf16
    ushort* WbT = hb + NE;                         // 12*16384 bf16
    float* eb   = (float*)(WbT + 12 * 16384);      // 3*NEDG*4 fp32

    prep_kernel<<<dim3(1024, 3), 256, 0, stream>>>(
        Wq, Wk, Wv, Wo, h_edges, We, be, h_nodes, WbT, eb, hb);

    for (int i = 0; i < NLL; ++i) {
        qkv_mfma<<<dim3(NROW / 128, 3), 256, 0, stream>>>(
            hb, WbT + (size_t)i * 4 * 16384,
            bq + i * HIDD, bk + i * HIDD, bv + i * HIDD,
            Qp, Kp, Vp);
        attn_kernel<<<NROW / 8, 256, 0, stream>>>(
            Qp, Kp, Vp, edge_idxs,
            (const float4*)eb + (size_t)i * NEDG, mask, obb);
        bool last = (i == NLL - 1);
        outproj_mfma<<<NROW / 128, 256, 0, stream>>>(
            obb, WbT + ((size_t)i * 4 + 3) * 16384, bo + i * HIDD,
            (i == 0) ? h_nodes : h,
            ln_g + i * HIDD, ln_b + i * HIDD, mask,
            last ? (float*)d_out : h, hb);
    }
}